// Round 7
// baseline (943.462 us; speedup 1.0000x reference)
//
#include <hip/hip_runtime.h>
#include <stdint.h>

#define B_N 16384
#define D_N 1024
#define H_N 4096

typedef int i32x4 __attribute__((ext_vector_type(4)));
typedef int i32x8 __attribute__((ext_vector_type(8)));
typedef float f32x4 __attribute__((ext_vector_type(4)));

__device__ __forceinline__ void gload16(const void* g, void* l) {
  __builtin_amdgcn_global_load_lds((const __attribute__((address_space(1))) void*)g,
                                   (__attribute__((address_space(3))) void*)l,
                                   16, 0, 0);
}

__device__ __forceinline__ unsigned char f2fp8(float v) {
  return (unsigned char)(__builtin_amdgcn_cvt_pk_fp8_f32(v, v, 0, false) & 0xFF);
}

// within-64-block H permutation used for Dh stores / W2T K-index:
// u = j*16+lm  ->  lm*4+j
__device__ __forceinline__ int perm_h(int h) {
  return (h & ~63) | ((h & 15) << 2) | ((h >> 4) & 3);
}

// ================= prep (single dispatch): pack X, transpose W1/W2 =========
__device__ __forceinline__ void transpose_tile(
    const float* __restrict__ in, unsigned char* __restrict__ out,
    int R, int C, float scale, float* __restrict__ w3, int pci,
    int i0, int j0, int tx, int ty, bool permute) {
  __shared__ float tile[32][33];
#pragma unroll
  for (int r = 0; r < 32; r += 8) {
    int i = i0 + ty + r;
    int j = j0 + tx;
    float v = in[(size_t)i * C + j];
    tile[ty + r][tx] = v;
    if (w3 != nullptr && i == pci) w3[j] = v;
  }
  __syncthreads();
#pragma unroll
  for (int r = 0; r < 32; r += 8) {
    int jo = j0 + ty + r;
    int io = i0 + tx;
    int ioo = permute ? perm_h(io) : io;
    out[(size_t)jo * R + ioo] = f2fp8(tile[tx][ty + r] * scale);
  }
}

__global__ __launch_bounds__(256) void prep_kernel(
    const float4* __restrict__ X4, int* __restrict__ Xb,
    float* __restrict__ s,
    const float* __restrict__ W1, unsigned char* __restrict__ W1T, float* __restrict__ w3,
    const float* __restrict__ W2, unsigned char* __restrict__ W2T,
    const int* __restrict__ pci_p, float* __restrict__ out0) {
  int b = blockIdx.x;
  int tid = threadIdx.x;
  int pci = *pci_p;
  if (b == 0 && tid == 0) out0[0] = 0.0f;   // zero the output accumulator
  if (b < 8192) {
    int i = (b * 256 + tid) * 2;
#pragma unroll
    for (int u = 0; u < 2; u++) {
      float4 v = X4[i + u];
      int p = __builtin_amdgcn_cvt_pk_fp8_f32(v.x, v.y, 0, false);
      p = __builtin_amdgcn_cvt_pk_fp8_f32(v.z, v.w, p, true);
      Xb[i + u] = p;
      if (((i + u) & (D_N / 4 - 1)) == (pci >> 2)) {
        int row = (i + u) >> 8;
        float c;
        switch (pci & 3) {
          case 0:  c = v.x; break;
          case 1:  c = v.y; break;
          case 2:  c = v.z; break;
          default: c = v.w; break;
        }
        s[row] = 1.0f - 2.0f * c;
      }
    }
  } else if (b < 12288) {
    // W1 (D_N x H_N) -> W1T[h][d] = W1[d][h]*16 ; rows h NOT permuted
    int id = b - 8192;
    transpose_tile(W1, W1T, D_N, H_N, 16.0f, w3, pci,
                   (id >> 7) * 32, (id & 127) * 32, tid & 31, tid >> 5, false);
  } else {
    // W2 (H_N x D_N) -> W2T[d][perm(h)] = W2[h][d]*64 ; K(=H) permuted
    int id = b - 12288;
    transpose_tile(W2, W2T, H_N, D_N, 64.0f, nullptr, -1,
                   (id >> 5) * 32, (id & 31) * 32, tid & 31, tid >> 5, true);
  }
}

// === MX-fp8 mainloop, 128x128 tile, 4 waves, 4 blocks/CU, B-direct ========
// A staged via gload_lds into a DOUBLE-BUFFERED 2x16KB LDS (pre-swizzled
// source, linear dest; reader XORs back). B-fragments loaded straight from
// global to VGPRs (two dwordx4 per frag) - B tiles are L2/L1-hot weights,
// so LDS read traffic halves and B-staging vanishes.
// Per K-tile, FIFO = [Ast(t)x4, B(t)x8, Ast(t+1)x4]: ONE vmcnt(4) completes
// Ast(t)+B(t) and leaves Ast(t+1) in flight across both barriers (never
// drains mid-loop). The count is robust to however many VMEM instructions
// the B loads compile to: vmcnt(4) retains exactly the 4 NEWEST entries,
// which are the Ast(t+1) gload_lds; B-register completion is additionally
// compiler-tracked. BARR1 after VM = cross-wave stage visibility for buf P;
// BARR2 after compute = buf-P reads precede next epoch's buf-P stage issue.
// B(t+1) issued after the MFMA cluster (sched_barrier) so b regs stay
// single-buffered: arch VGPR ~56 + 64 AGPR acc -> 4 waves/SIMD holds.
template <int KTOT>
__device__ __forceinline__ void mx_bd_mainloop(
    const unsigned char* __restrict__ A, const unsigned char* __restrict__ Bm,
    int m0, int n0, int sa, int sb,
    unsigned char* __restrict__ As, f32x4 (&acc)[4][4]) {
  const int tid = threadIdx.x;
  const int lane = tid & 63;
  const int wave = tid >> 6;
  const int wm = (wave >> 1) * 64;
  const int wn = (wave & 1) * 64;
  const int lm = lane & 15;
  const int quad = lane >> 4;

  // A staging: 128 rows x 128B per buffer; thread covers rows srow+32*it
  const int srow = tid >> 3;
  const int sg = tid & 7;
  const unsigned char* Ag = A + (size_t)(m0 + srow) * KTOT + ((sg ^ (srow & 7)) * 16);
  unsigned char* AsW = As + tid * 16;

  // A fragment read bases (XOR undo is thread-constant: e = lm&7)
  const int e = lm & 7;
  const unsigned char* Ard_lo = As + (wm + lm) * 128 + (((2 * quad) ^ e) * 16);
  const unsigned char* Ard_hi = As + (wm + lm) * 128 + (((2 * quad + 1) ^ e) * 16);

  // B direct: frag j = rows n0+wn+j*16+lm, k-bytes [32q, 32q+32)
  const unsigned char* Bg0 = Bm + (size_t)(n0 + wn + lm) * KTOT + 32 * quad;

  i32x8 b0, b1, b2, b3;

#define STG(it_, kn_, p_) gload16(Ag + (kn_) + (size_t)(32 * (it_)) * KTOT, \
                                  AsW + (p_) * 16384 + (it_) * 4096)
#define LDBG(d_, j_, kn_) { \
    const unsigned char* p_ = Bg0 + (size_t)(j_) * 16 * KTOT + (kn_); \
    i32x4 lo_ = *(const i32x4*)(p_); \
    i32x4 hi_ = *(const i32x4*)(p_ + 16); \
    d_ = __builtin_shufflevector(lo_, hi_, 0, 1, 2, 3, 4, 5, 6, 7); }
#define LDA(d_, i_, P_) { \
    i32x4 lo_ = *(const i32x4*)(Ard_lo + (P_) * 16384 + (i_) * 2048); \
    i32x4 hi_ = *(const i32x4*)(Ard_hi + (P_) * 16384 + (i_) * 2048); \
    d_ = __builtin_shufflevector(lo_, hi_, 0, 1, 2, 3, 4, 5, 6, 7); }
#define MF(a_, b_, c_) \
    __builtin_amdgcn_mfma_scale_f32_16x16x128_f8f6f4((a_), (b_), (c_), 0, 0, 0, sa, 0, sb)
#define BARR() { asm volatile("" ::: "memory"); __builtin_amdgcn_s_barrier(); \
                 asm volatile("" ::: "memory"); }
#define ROW(i_, P_) { i32x8 a_; LDA(a_, i_, P_); \
    acc[i_][0] = MF(a_, b0, acc[i_][0]); \
    acc[i_][1] = MF(a_, b1, acc[i_][1]); \
    acc[i_][2] = MF(a_, b2, acc[i_][2]); \
    acc[i_][3] = MF(a_, b3, acc[i_][3]); }

  // Prologue: stage A(0) -> buf0, issue B(0). FIFO = [Ast0 x4, B0 x8].
  STG(0, 0, 0); STG(1, 0, 0); STG(2, 0, 0); STG(3, 0, 0);
  LDBG(b0, 0, 0); LDBG(b1, 1, 0); LDBG(b2, 2, 0); LDBG(b3, 3, 0);

  const int NT = KTOT / 128;
#pragma unroll 1
  for (int t = 0; t < NT; ++t) {
    const int P = t & 1;
    const bool pf = (t + 1 < NT);
    const int kn = (t + 1) * 128;
    if (pf) { STG(0, kn, 1 - P); STG(1, kn, 1 - P);
              STG(2, kn, 1 - P); STG(3, kn, 1 - P); }
    // completes Ast(t)+B(t), leaves Ast(t+1) in flight
    if (pf) { asm volatile("s_waitcnt vmcnt(4)" ::: "memory"); }
    else    { asm volatile("s_waitcnt vmcnt(0)" ::: "memory"); }
    BARR();                       // all waves' Ast(t) visible
    ROW(0, P); ROW(1, P); ROW(2, P); ROW(3, P);
    __builtin_amdgcn_sched_barrier(0);
    if (pf) { LDBG(b0, 0, kn); LDBG(b1, 1, kn);
              LDBG(b2, 2, kn); LDBG(b3, 3, kn); }
    BARR();                       // buf-P reads done before next buf-P stage
  }

#undef STG
#undef LDBG
#undef LDA
#undef MF
#undef BARR
#undef ROW
}

// ---- GEMM1: Z = X @ W1, epilogue Dh = 64*(tanh(z)-tanh(z+s*w3)) -> fp8 ----
// Grid 4096 = 4 exact generations at 4 blocks/CU. m_t = x*16+m in BOTH gemms
// so Dh panels stay on one XCD's L2; W1T n-slice 1 MB/generation L2-hot.
__global__ __launch_bounds__(256, 4) void gemm1_dh(
    const unsigned char* __restrict__ Xb,    // B_N x D_N fp8 (x1)
    const unsigned char* __restrict__ W1T,   // H_N x D_N fp8 (x16)
    const float* __restrict__ b1,
    const float* __restrict__ w3,            // H_N : W1[pci][h] f32
    const float* __restrict__ s,             // B_N : 1-2*col
    unsigned int* __restrict__ Dh4) {        // B_N x H_N fp8 (x64), perm'd cols
  __shared__ alignas(16) unsigned char As[32768];
  int l = blockIdx.y * gridDim.x + blockIdx.x;  // HW dispatch-linear
  int x = l & 7;                                // XCD round-robin
  int k = l >> 3;                               // 0..511 per XCD
  int ni = k & 7;
  int m  = (k >> 3) & 15;
  int nc = k >> 7;                              // 0..3
  const int m0 = (x * 16 + m) * 128;
  const int n0 = (nc * 8 + ni) * 128;

  f32x4 acc[4][4] = {};
  mx_bd_mainloop<D_N>(Xb, W1T, m0, n0, 127, 123, As, acc);  // 2^0 * 2^-4

  const int tid = threadIdx.x;
  const int lane = tid & 63;
  const int wave = tid >> 6;
  const int wm = (wave >> 1) * 64;
  const int wn = (wave & 1) * 64;
  const int lm = lane & 15;
  const int quad = lane >> 4;

  float ewp[4], ewm[4], nump[4], numm[4], b1v[4];
#pragma unroll
  for (int j = 0; j < 4; j++) {
    int gh = n0 + wn + j * 16 + lm;
    float w = w3[gh];
    float ep = __expf(2.0f * w);
    float em = __expf(-2.0f * w);
    ewp[j] = ep; ewm[j] = em;
    nump[j] = 128.0f * (1.0f - ep);
    numm[j] = 128.0f * (1.0f - em);
    b1v[j] = b1[gh];
  }
  const size_t coloff = (size_t)((n0 + wn) >> 2) + lm;
#pragma unroll
  for (int i = 0; i < 4; i++) {
#pragma unroll
    for (int r = 0; r < 4; r++) {
      int gb = m0 + wm + i * 16 + quad * 4 + r;
      bool sp = s[gb] > 0.0f;
      float o[4];
#pragma unroll
      for (int j = 0; j < 4; j++) {
        float ews = sp ? ewp[j] : ewm[j];
        float num = sp ? nump[j] : numm[j];
        float z = fminf(acc[i][j][r] + b1v[j], 12.0f);
        float E = __expf(2.0f * z);
        float den = (E * ews + 1.0f) * (E + 1.0f);
        o[j] = (E * num) * __builtin_amdgcn_rcpf(den);  // 64*dh
      }
      int p = __builtin_amdgcn_cvt_pk_fp8_f32(o[0], o[1], 0, false);
      p = __builtin_amdgcn_cvt_pk_fp8_f32(o[2], o[3], p, true);
      Dh4[(size_t)gb * (H_N / 4) + coloff] = (unsigned int)p;
    }
  }
}

// ---- GEMM2: Y = Dh @ W2, epilogue mean-scaled sum|Y| -> atomic d_out ----
// Grid 1024 = ONE exact generation at 4 blocks/CU; same m<->XCD map.
__global__ __launch_bounds__(256, 4) void gemm2_abs(
    const unsigned char* __restrict__ Dh,    // B_N x H_N fp8 (x64), perm'd K
    const unsigned char* __restrict__ W2T,   // D_N x H_N fp8 (x64), perm'd K
    float* __restrict__ out) {
  __shared__ alignas(16) unsigned char As[32768];
  __shared__ float wsum[4];
  int l = blockIdx.y * gridDim.x + blockIdx.x;
  int x = l & 7;
  int k = l >> 3;                               // 0..127 per XCD
  int c = k >> 6;                               // ni-chunk 0..1
  int idx = k & 63;
  int m  = idx >> 2;                            // 0..15 (same m<->XCD map)
  int nj = idx & 3;
  const int m0 = (x * 16 + m) * 128;
  const int n0 = (c * 4 + nj) * 128;

  f32x4 acc[4][4] = {};
  mx_bd_mainloop<H_N>(Dh, W2T, m0, n0, 121, 121, As, acc);  // 2^-6 * 2^-6

  const int tid = threadIdx.x;
  const int lane = tid & 63;
  const int wave = tid >> 6;

  float t = 0.0f;
#pragma unroll
  for (int i = 0; i < 4; i++)
#pragma unroll
    for (int j = 0; j < 4; j++)
#pragma unroll
      for (int r = 0; r < 4; r++)
        t += fabsf(acc[i][j][r]);

#pragma unroll
  for (int off2 = 32; off2 > 0; off2 >>= 1)
    t += __shfl_down(t, off2, 64);
  if (lane == 0) wsum[wave] = t;
  __syncthreads();
  if (tid == 0)
    atomicAdd(out, (wsum[0] + wsum[1] + wsum[2] + wsum[3]) * (1.0f / (float)B_N));
}

extern "C" void kernel_launch(void* const* d_in, const int* in_sizes, int n_in,
                              void* d_out, int out_size, void* d_ws, size_t ws_size,
                              hipStream_t stream) {
  const float* X  = (const float*)d_in[0];
  const float* W1 = (const float*)d_in[1];
  const float* b1 = (const float*)d_in[2];
  const float* W2 = (const float*)d_in[3];
  // d_in[4] = b2 : cancels in the difference
  const int* pci  = (const int*)d_in[5];

  char* ws = (char*)d_ws;
  size_t off = 0;
  unsigned char* Xb  = (unsigned char*)(ws + off); off += (size_t)B_N * D_N;
  unsigned char* W1T = (unsigned char*)(ws + off); off += (size_t)H_N * D_N;
  unsigned char* W2T = (unsigned char*)(ws + off); off += (size_t)D_N * H_N;
  float* w3  = (float*)(ws + off); off += (size_t)H_N * 4;
  float* s   = (float*)(ws + off); off += (size_t)B_N * 4;
  unsigned char* Dh  = (unsigned char*)(ws + off); off += (size_t)B_N * H_N;
  if (ws_size < off) return;

  prep_kernel<<<16384, 256, 0, stream>>>((const float4*)X, (int*)Xb, s,
                                         W1, W1T, w3, W2, W2T, pci,
                                         (float*)d_out);
  gemm1_dh<<<dim3(32, 128), 256, 0, stream>>>(Xb, W1T, b1, w3, s,
                                              (unsigned int*)Dh);
  gemm2_abs<<<dim3(8, 128), 256, 0, stream>>>(Dh, W2T, (float*)d_out);
}

// Round 8
// 933.476 us; speedup vs baseline: 1.0107x; 1.0107x over previous
//
#include <hip/hip_runtime.h>
#include <stdint.h>

#define B_N 16384
#define D_N 1024
#define H_N 4096

typedef int i32x4 __attribute__((ext_vector_type(4)));
typedef int i32x8 __attribute__((ext_vector_type(8)));
typedef float f32x4 __attribute__((ext_vector_type(4)));

__device__ __forceinline__ void gload16(const void* g, void* l) {
  __builtin_amdgcn_global_load_lds((const __attribute__((address_space(1))) void*)g,
                                   (__attribute__((address_space(3))) void*)l,
                                   16, 0, 0);
}

__device__ __forceinline__ unsigned char f2fp8(float v) {
  return (unsigned char)(__builtin_amdgcn_cvt_pk_fp8_f32(v, v, 0, false) & 0xFF);
}

// within-64-block H permutation used for Dh stores / W2T K-index:
// u = j*16+lm  ->  lm*4+j
__device__ __forceinline__ int perm_h(int h) {
  return (h & ~63) | ((h & 15) << 2) | ((h >> 4) & 3);
}

// B-operand fragment-major layout: the 32 bytes lane l=q*16+lm of fragment
// (n-group g = row>>4, k-tile kt = kk>>7) needs are stored contiguously at
// ((g*NKT+kt)<<11) + l*32.  row = B-operand n-row, kk = k-byte (perm'd for W2).
__device__ __forceinline__ size_t fragB_addr(int row, int kk, int NKT) {
  return ((size_t)((row >> 4) * NKT + (kk >> 7)) << 11)
       + (size_t)((((kk >> 5) & 3) << 4) + (row & 15)) * 32 + (kk & 31);
}

// ================= prep (single dispatch): pack X, transpose W1/W2 =========
__device__ __forceinline__ void transpose_tile(
    const float* __restrict__ in, unsigned char* __restrict__ out,
    int R, int C, float scale, float* __restrict__ w3, int pci,
    int i0, int j0, int tx, int ty, bool permute) {
  __shared__ float tile[32][33];
#pragma unroll
  for (int r = 0; r < 32; r += 8) {
    int i = i0 + ty + r;
    int j = j0 + tx;
    float v = in[(size_t)i * C + j];
    tile[ty + r][tx] = v;
    if (w3 != nullptr && i == pci) w3[j] = v;
  }
  __syncthreads();
#pragma unroll
  for (int r = 0; r < 32; r += 8) {
    int jo = j0 + ty + r;            // B-operand row (h for W1, d for W2)
    int io = i0 + tx;                // k index      (d for W1, h for W2)
    int kk = permute ? perm_h(io) : io;
    out[fragB_addr(jo, kk, R >> 7)] = f2fp8(tile[tx][ty + r] * scale);
  }
}

__global__ __launch_bounds__(256) void prep_kernel(
    const float4* __restrict__ X4, int* __restrict__ Xb,
    float* __restrict__ s,
    const float* __restrict__ W1, unsigned char* __restrict__ W1T, float* __restrict__ w3,
    const float* __restrict__ W2, unsigned char* __restrict__ W2T,
    const int* __restrict__ pci_p, float* __restrict__ out0) {
  int b = blockIdx.x;
  int tid = threadIdx.x;
  int pci = *pci_p;
  if (b == 0 && tid == 0) out0[0] = 0.0f;   // zero the output accumulator
  if (b < 8192) {
    int i = (b * 256 + tid) * 2;
#pragma unroll
    for (int u = 0; u < 2; u++) {
      float4 v = X4[i + u];
      int p = __builtin_amdgcn_cvt_pk_fp8_f32(v.x, v.y, 0, false);
      p = __builtin_amdgcn_cvt_pk_fp8_f32(v.z, v.w, p, true);
      Xb[i + u] = p;
      if (((i + u) & (D_N / 4 - 1)) == (pci >> 2)) {
        int row = (i + u) >> 8;
        float c;
        switch (pci & 3) {
          case 0:  c = v.x; break;
          case 1:  c = v.y; break;
          case 2:  c = v.z; break;
          default: c = v.w; break;
        }
        s[row] = 1.0f - 2.0f * c;
      }
    }
  } else if (b < 12288) {
    // W1 (D_N x H_N) -> frag-major W1F[h-group][d-ktile]; rows h NOT permuted
    int id = b - 8192;
    transpose_tile(W1, W1T, D_N, H_N, 16.0f, w3, pci,
                   (id >> 7) * 32, (id & 127) * 32, tid & 31, tid >> 5, false);
  } else {
    // W2 (H_N x D_N) -> frag-major W2F[d-group][perm(h)-ktile]; K(=H) permuted
    int id = b - 12288;
    transpose_tile(W2, W2T, H_N, D_N, 64.0f, nullptr, -1,
                   (id >> 5) * 32, (id & 31) * 32, tid & 31, tid >> 5, true);
  }
}

// === MX-fp8 mainloop, 128x128 tile, 4 waves, 4 blocks/CU, B-direct(coal) ===
// A staged via gload_lds into a DOUBLE-BUFFERED 2x16KB LDS (pre-swizzled
// source, linear dest; reader XORs back).  B-fragments loaded straight from
// global to VGPRs from the FRAGMENT-MAJOR layout: one i32x8 per frag at
// base + (j*NKT+kt)*2048 + lane*32  -> 64 lanes x 32 B CONTIGUOUS (2 KB),
// L1/L2-perfect.  No B staging, LDS read traffic halves vs round 0.
// vmcnt ledger (B = 8 VMEM/tile, Ast = 4 gload_lds/tile):
//   steady state at tile t start: FIFO = [Ast(t)x4? no: [B(t)x8? ...]
//   trace: prologue [A0x4,B0x8]; each tile: +Ast(t+1)x4 -> VM(4) completes
//   A(t)stage+B(t) regs, leaves Ast(t+1) in flight across both barriers.
// BARR1 (after VM) = cross-wave A(t) visibility; BARR2 (tile end) = buf-P
// ds_reads complete (they feed MFMAs -> lgkm-drained before barrier) before
// next tile's STG into buf P.  Never drains vmcnt to 0 mid-loop.
template <int KTOT>
__device__ __forceinline__ void mx_bd_mainloop(
    const unsigned char* __restrict__ A, const unsigned char* __restrict__ BF,
    int m0, int n0, int sa, int sb,
    unsigned char* __restrict__ As, f32x4 (&acc)[4][4]) {
  const int NKT = KTOT / 128;
  const int tid = threadIdx.x;
  const int lane = tid & 63;
  const int wave = tid >> 6;
  const int wm = (wave >> 1) * 64;
  const int wn = (wave & 1) * 64;
  const int lm = lane & 15;
  const int quad = lane >> 4;

  // A staging: 128 rows x 128B per buffer; thread covers rows srow+32*it
  const int srow = tid >> 3;
  const int sg = tid & 7;
  const unsigned char* Ag = A + (size_t)(m0 + srow) * KTOT + ((sg ^ (srow & 7)) * 16);
  unsigned char* AsW = As + tid * 16;

  // A fragment read bases (XOR undo is thread-constant: e = lm&7)
  const int e = lm & 7;
  const unsigned char* Ard_lo = As + (wm + lm) * 128 + (((2 * quad) ^ e) * 16);
  const unsigned char* Ard_hi = As + (wm + lm) * 128 + (((2 * quad + 1) ^ e) * 16);

  // B fragment-major base: group g0 = (n0+wn)>>4, lane offset built in
  const unsigned char* BgF = BF + (((size_t)((n0 + wn) >> 4) * NKT) << 11) + lane * 32;

  i32x8 b0, b1, b2, b3;

#define STG(it_, kn_, p_) gload16(Ag + (kn_) + (size_t)(32 * (it_)) * KTOT, \
                                  AsW + (p_) * 16384 + (it_) * 4096)
#define LDBG(d_, j_, kt_) \
    d_ = *(const i32x8*)(BgF + (((size_t)(j_) * NKT + (kt_)) << 11))
#define LDA(d_, i_, P_) { \
    i32x4 lo_ = *(const i32x4*)(Ard_lo + (P_) * 16384 + (i_) * 2048); \
    i32x4 hi_ = *(const i32x4*)(Ard_hi + (P_) * 16384 + (i_) * 2048); \
    d_ = __builtin_shufflevector(lo_, hi_, 0, 1, 2, 3, 4, 5, 6, 7); }
#define MF(a_, b_, c_) \
    __builtin_amdgcn_mfma_scale_f32_16x16x128_f8f6f4((a_), (b_), (c_), 0, 0, 0, sa, 0, sb)
#define BARR() { asm volatile("" ::: "memory"); __builtin_amdgcn_s_barrier(); \
                 asm volatile("" ::: "memory"); }
#define ROW(i_, P_) { i32x8 a_; LDA(a_, i_, P_); \
    acc[i_][0] = MF(a_, b0, acc[i_][0]); \
    acc[i_][1] = MF(a_, b1, acc[i_][1]); \
    acc[i_][2] = MF(a_, b2, acc[i_][2]); \
    acc[i_][3] = MF(a_, b3, acc[i_][3]); }

  // Prologue: stage A(0) -> buf0, issue B(0). FIFO = [Ast0 x4, B0 x8].
  STG(0, 0, 0); STG(1, 0, 0); STG(2, 0, 0); STG(3, 0, 0);
  LDBG(b0, 0, 0); LDBG(b1, 1, 0); LDBG(b2, 2, 0); LDBG(b3, 3, 0);

  const int NT = KTOT / 128;
#pragma unroll 1
  for (int t = 0; t < NT; ++t) {
    const int P = t & 1;
    const bool pf = (t + 1 < NT);
    const int kn = (t + 1) * 128;
    if (pf) { STG(0, kn, 1 - P); STG(1, kn, 1 - P);
              STG(2, kn, 1 - P); STG(3, kn, 1 - P); }
    // completes A(t) stage + B(t) regs; leaves Ast(t+1) in flight
    if (pf) { asm volatile("s_waitcnt vmcnt(4)" ::: "memory"); }
    else    { asm volatile("s_waitcnt vmcnt(0)" ::: "memory"); }
    BARR();                       // all waves' A(t) visible
    ROW(0, P); ROW(1, P); ROW(2, P); ROW(3, P);
    __builtin_amdgcn_sched_barrier(0);
    if (pf) { LDBG(b0, 0, t + 1); LDBG(b1, 1, t + 1);
              LDBG(b2, 2, t + 1); LDBG(b3, 3, t + 1); }
    BARR();                       // buf-P reads done before next buf-P stage
  }

#undef STG
#undef LDBG
#undef LDA
#undef MF
#undef BARR
#undef ROW
}

// ---- GEMM1: Z = X @ W1, epilogue Dh = 64*(tanh(z)-tanh(z+s*w3)) -> fp8 ----
// Grid 4096 = 4 exact generations at 4 blocks/CU. m_t = x*16+m in BOTH gemms
// so Dh panels stay on one XCD's L2; W1F n-slice 1 MB/generation L2-hot.
__global__ __launch_bounds__(256, 4) void gemm1_dh(
    const unsigned char* __restrict__ Xb,    // B_N x D_N fp8 (x1)
    const unsigned char* __restrict__ W1T,   // frag-major W1F (x16)
    const float* __restrict__ b1,
    const float* __restrict__ w3,            // H_N : W1[pci][h] f32
    const float* __restrict__ s,             // B_N : 1-2*col
    unsigned int* __restrict__ Dh4) {        // B_N x H_N fp8 (x64), perm'd cols
  __shared__ alignas(16) unsigned char As[32768];
  int l = blockIdx.y * gridDim.x + blockIdx.x;  // HW dispatch-linear
  int x = l & 7;                                // XCD round-robin
  int k = l >> 3;                               // 0..511 per XCD
  int ni = k & 7;
  int m  = (k >> 3) & 15;
  int nc = k >> 7;                              // 0..3
  const int m0 = (x * 16 + m) * 128;
  const int n0 = (nc * 8 + ni) * 128;

  f32x4 acc[4][4] = {};
  mx_bd_mainloop<D_N>(Xb, W1T, m0, n0, 127, 123, As, acc);  // 2^0 * 2^-4

  const int tid = threadIdx.x;
  const int lane = tid & 63;
  const int wave = tid >> 6;
  const int wm = (wave >> 1) * 64;
  const int wn = (wave & 1) * 64;
  const int lm = lane & 15;
  const int quad = lane >> 4;

  float ewp[4], ewm[4], nump[4], numm[4], b1v[4];
#pragma unroll
  for (int j = 0; j < 4; j++) {
    int gh = n0 + wn + j * 16 + lm;
    float w = w3[gh];
    float ep = __expf(2.0f * w);
    float em = __expf(-2.0f * w);
    ewp[j] = ep; ewm[j] = em;
    nump[j] = 128.0f * (1.0f - ep);
    numm[j] = 128.0f * (1.0f - em);
    b1v[j] = b1[gh];
  }
  const size_t coloff = (size_t)((n0 + wn) >> 2) + lm;
#pragma unroll
  for (int i = 0; i < 4; i++) {
#pragma unroll
    for (int r = 0; r < 4; r++) {
      int gb = m0 + wm + i * 16 + quad * 4 + r;
      bool sp = s[gb] > 0.0f;
      float o[4];
#pragma unroll
      for (int j = 0; j < 4; j++) {
        float ews = sp ? ewp[j] : ewm[j];
        float num = sp ? nump[j] : numm[j];
        float z = fminf(acc[i][j][r] + b1v[j], 12.0f);
        float E = __expf(2.0f * z);
        float den = (E * ews + 1.0f) * (E + 1.0f);
        o[j] = (E * num) * __builtin_amdgcn_rcpf(den);  // 64*dh
      }
      int p = __builtin_amdgcn_cvt_pk_fp8_f32(o[0], o[1], 0, false);
      p = __builtin_amdgcn_cvt_pk_fp8_f32(o[2], o[3], p, true);
      Dh4[(size_t)gb * (H_N / 4) + coloff] = (unsigned int)p;
    }
  }
}

// ---- GEMM2: Y = Dh @ W2, epilogue mean-scaled sum|Y| -> atomic d_out ----
// Grid 1024 = ONE exact generation at 4 blocks/CU; same m<->XCD map.
__global__ __launch_bounds__(256, 4) void gemm2_abs(
    const unsigned char* __restrict__ Dh,    // B_N x H_N fp8 (x64), perm'd K
    const unsigned char* __restrict__ W2T,   // frag-major W2F (x64), perm'd K
    float* __restrict__ out) {
  __shared__ alignas(16) unsigned char As[32768];
  __shared__ float wsum[4];
  int l = blockIdx.y * gridDim.x + blockIdx.x;
  int x = l & 7;
  int k = l >> 3;                               // 0..127 per XCD
  int c = k >> 6;                               // ni-chunk 0..1
  int idx = k & 63;
  int m  = idx >> 2;                            // 0..15 (same m<->XCD map)
  int nj = idx & 3;
  const int m0 = (x * 16 + m) * 128;
  const int n0 = (c * 4 + nj) * 128;

  f32x4 acc[4][4] = {};
  mx_bd_mainloop<H_N>(Dh, W2T, m0, n0, 121, 121, As, acc);  // 2^-6 * 2^-6

  const int tid = threadIdx.x;
  const int lane = tid & 63;
  const int wave = tid >> 6;

  float t = 0.0f;
#pragma unroll
  for (int i = 0; i < 4; i++)
#pragma unroll
    for (int j = 0; j < 4; j++)
#pragma unroll
      for (int r = 0; r < 4; r++)
        t += fabsf(acc[i][j][r]);

#pragma unroll
  for (int off2 = 32; off2 > 0; off2 >>= 1)
    t += __shfl_down(t, off2, 64);
  if (lane == 0) wsum[wave] = t;
  __syncthreads();
  if (tid == 0)
    atomicAdd(out, (wsum[0] + wsum[1] + wsum[2] + wsum[3]) * (1.0f / (float)B_N));
}

extern "C" void kernel_launch(void* const* d_in, const int* in_sizes, int n_in,
                              void* d_out, int out_size, void* d_ws, size_t ws_size,
                              hipStream_t stream) {
  const float* X  = (const float*)d_in[0];
  const float* W1 = (const float*)d_in[1];
  const float* b1 = (const float*)d_in[2];
  const float* W2 = (const float*)d_in[3];
  // d_in[4] = b2 : cancels in the difference
  const int* pci  = (const int*)d_in[5];

  char* ws = (char*)d_ws;
  size_t off = 0;
  unsigned char* Xb  = (unsigned char*)(ws + off); off += (size_t)B_N * D_N;
  unsigned char* W1T = (unsigned char*)(ws + off); off += (size_t)H_N * D_N;
  unsigned char* W2T = (unsigned char*)(ws + off); off += (size_t)D_N * H_N;
  float* w3  = (float*)(ws + off); off += (size_t)H_N * 4;
  float* s   = (float*)(ws + off); off += (size_t)B_N * 4;
  unsigned char* Dh  = (unsigned char*)(ws + off); off += (size_t)B_N * H_N;
  if (ws_size < off) return;

  prep_kernel<<<16384, 256, 0, stream>>>((const float4*)X, (int*)Xb, s,
                                         W1, W1T, w3, W2, W2T, pci,
                                         (float*)d_out);
  gemm1_dh<<<dim3(32, 128), 256, 0, stream>>>(Xb, W1T, b1, w3, s,
                                              (unsigned int*)Dh);
  gemm2_abs<<<dim3(8, 128), 256, 0, stream>>>(Dh, W2T, (float*)d_out);
}

// Round 9
// 276.053 us; speedup vs baseline: 3.4177x; 3.3815x over previous
//
#include <hip/hip_runtime.h>
#include <stdint.h>

#define B_N 16384
#define D_N 1024
#define H_N 4096

typedef int i32x4 __attribute__((ext_vector_type(4)));
typedef int i32x8 __attribute__((ext_vector_type(8)));
typedef float f32x4 __attribute__((ext_vector_type(4)));

__device__ __forceinline__ void gload16(const void* g, void* l) {
  __builtin_amdgcn_global_load_lds((const __attribute__((address_space(1))) void*)g,
                                   (__attribute__((address_space(3))) void*)l,
                                   16, 0, 0);
}

__device__ __forceinline__ unsigned char f2fp8(float v) {
  return (unsigned char)(__builtin_amdgcn_cvt_pk_fp8_f32(v, v, 0, false) & 0xFF);
}

// within-64-block H permutation used for Dh stores / W2T K-index:
// u = j*16+lm  ->  lm*4+j
__device__ __forceinline__ int perm_h(int h) {
  return (h & ~63) | ((h & 15) << 2) | ((h >> 4) & 3);
}

// ================= prep (single dispatch): pack X, transpose W1/W2 =========
__device__ __forceinline__ void transpose_tile(
    const float* __restrict__ in, unsigned char* __restrict__ out,
    int R, int C, float scale, float* __restrict__ w3, int pci,
    int i0, int j0, int tx, int ty, bool permute) {
  __shared__ float tile[32][33];
#pragma unroll
  for (int r = 0; r < 32; r += 8) {
    int i = i0 + ty + r;
    int j = j0 + tx;
    float v = in[(size_t)i * C + j];
    tile[ty + r][tx] = v;
    if (w3 != nullptr && i == pci) w3[j] = v;
  }
  __syncthreads();
#pragma unroll
  for (int r = 0; r < 32; r += 8) {
    int jo = j0 + ty + r;
    int io = i0 + tx;
    int ioo = permute ? perm_h(io) : io;
    out[(size_t)jo * R + ioo] = f2fp8(tile[tx][ty + r] * scale);
  }
}

__global__ __launch_bounds__(256) void prep_kernel(
    const float4* __restrict__ X4, int* __restrict__ Xb,
    float* __restrict__ s,
    const float* __restrict__ W1, unsigned char* __restrict__ W1T, float* __restrict__ w3,
    const float* __restrict__ W2, unsigned char* __restrict__ W2T,
    const int* __restrict__ pci_p, float* __restrict__ out0) {
  int b = blockIdx.x;
  int tid = threadIdx.x;
  int pci = *pci_p;
  if (b == 0 && tid == 0) out0[0] = 0.0f;   // zero the output accumulator
  if (b < 8192) {
    int i = (b * 256 + tid) * 2;
#pragma unroll
    for (int u = 0; u < 2; u++) {
      float4 v = X4[i + u];
      int p = __builtin_amdgcn_cvt_pk_fp8_f32(v.x, v.y, 0, false);
      p = __builtin_amdgcn_cvt_pk_fp8_f32(v.z, v.w, p, true);
      Xb[i + u] = p;
      if (((i + u) & (D_N / 4 - 1)) == (pci >> 2)) {
        int row = (i + u) >> 8;
        float c;
        switch (pci & 3) {
          case 0:  c = v.x; break;
          case 1:  c = v.y; break;
          case 2:  c = v.z; break;
          default: c = v.w; break;
        }
        s[row] = 1.0f - 2.0f * c;
      }
    }
  } else if (b < 12288) {
    // W1 (D_N x H_N) -> W1T[h][d] = W1[d][h]*16 ; rows h NOT permuted
    int id = b - 8192;
    transpose_tile(W1, W1T, D_N, H_N, 16.0f, w3, pci,
                   (id >> 7) * 32, (id & 127) * 32, tid & 31, tid >> 5, false);
  } else {
    // W2 (H_N x D_N) -> W2T[d][perm(h)] = W2[h][d]*64 ; K(=H) permuted
    int id = b - 12288;
    transpose_tile(W2, W2T, H_N, D_N, 64.0f, nullptr, -1,
                   (id >> 5) * 32, (id & 31) * 32, tid & 31, tid >> 5, true);
  }
}

// ---- MX-fp8 K=128 mainloop for GEMM1 (round-0 verified): 128x128 tile, ----
// 4 waves, 4 blocks/CU. C(128x128) += A_tile x B_tile^T over KTOT.
// LDS XOR-swizzled on the global gather side; reader XORs back.
// Register-lean: hold b[0..3] (32 VGPR) + one a fragment (8) so that with the
// 64-AGPR accumulator the kernel fits 128 regs -> 4 waves/SIMD (lb 256,4).
template <int KTOT>
__device__ __forceinline__ void mx_mainloop(
    const unsigned char* __restrict__ A, const unsigned char* __restrict__ B,
    int m0, int n0, int sa, int sb,
    unsigned char* As, unsigned char* Bs, f32x4 (&acc)[4][4]) {
  const int tid = threadIdx.x;
  const int lane = tid & 63;
  const int wave = tid >> 6;
  const int wm = (wave >> 1) * 64;
  const int wn = (wave & 1) * 64;
  const int lm = lane & 15;
  const int quad = lane >> 4;

  const int srow = tid >> 3;
  const int clog = (tid & 7) ^ (srow & 7);
  const unsigned char* Ag = A + (size_t)(m0 + srow) * KTOT + clog * 16;
  const unsigned char* Bg = B + (size_t)(n0 + srow) * KTOT + clog * 16;
  unsigned char* As_l = As + tid * 16;
  unsigned char* Bs_l = Bs + tid * 16;

  for (int k0 = 0; k0 < KTOT; k0 += 128) {
#pragma unroll
    for (int it = 0; it < 4; it++) {
      gload16(Ag + k0 + (size_t)(32 * it) * KTOT, As_l + it * 4096);
      gload16(Bg + k0 + (size_t)(32 * it) * KTOT, Bs_l + it * 4096);
    }
    __syncthreads();
    i32x8 b[4];
#pragma unroll
    for (int j = 0; j < 4; j++) {
      int r = wn + j * 16 + lm;
      int e = r & 7;
      i32x4 lo = *(const i32x4*)&Bs[r * 128 + ((2 * quad) ^ e) * 16];
      i32x4 hi = *(const i32x4*)&Bs[r * 128 + ((2 * quad + 1) ^ e) * 16];
      b[j] = __builtin_shufflevector(lo, hi, 0, 1, 2, 3, 4, 5, 6, 7);
    }
#pragma unroll
    for (int i = 0; i < 4; i++) {
      int r = wm + i * 16 + lm;
      int e = r & 7;
      i32x4 lo = *(const i32x4*)&As[r * 128 + ((2 * quad) ^ e) * 16];
      i32x4 hi = *(const i32x4*)&As[r * 128 + ((2 * quad + 1) ^ e) * 16];
      i32x8 av = __builtin_shufflevector(lo, hi, 0, 1, 2, 3, 4, 5, 6, 7);
#pragma unroll
      for (int j = 0; j < 4; j++)
        acc[i][j] = __builtin_amdgcn_mfma_scale_f32_16x16x128_f8f6f4(
            av, b[j], acc[i][j], 0, 0, 0, sa, 0, sb);
    }
    __syncthreads();
  }
}

// ---- GEMM1: Z = X @ W1, epilogue Dh = 64*(tanh(z)-tanh(z+s*w3)) -> fp8 ----
// Round-0 verified: per XCD x, n-chunks of 8 tiles (1 MB W1T L2-hot), 16
// m-panels per chunk. m-rows 2048x..2048x+2047 owned by XCD x in BOTH gemms
// so Dh panels stay on one XCD's L2. Grid 4096 = 4 generations, 4 blocks/CU.
__global__ __launch_bounds__(256, 4) void gemm1_dh(
    const unsigned char* __restrict__ Xb,    // B_N x D_N fp8 (x1)
    const unsigned char* __restrict__ W1T,   // H_N x D_N fp8 (x16)
    const float* __restrict__ b1,
    const float* __restrict__ w3,            // H_N : W1[pci][h] f32
    const float* __restrict__ s,             // B_N : 1-2*col
    unsigned int* __restrict__ Dh4) {        // B_N x H_N fp8 (x64), perm'd cols
  __shared__ alignas(16) unsigned char As[128 * 128];
  __shared__ alignas(16) unsigned char Bs[128 * 128];
  int l = blockIdx.y * gridDim.x + blockIdx.x;  // HW dispatch-linear
  int x = l & 7;                                // XCD round-robin
  int k = l >> 3;                               // 0..511 per XCD
  int ni = k & 7;
  int m  = (k >> 3) & 15;
  int nc = k >> 7;                              // 0..3
  const int m0 = (x * 16 + m) * 128;
  const int n0 = (nc * 8 + ni) * 128;

  f32x4 acc[4][4] = {};
  mx_mainloop<D_N>(Xb, W1T, m0, n0, 127, 123, As, Bs, acc);  // 2^0 * 2^-4

  const int tid = threadIdx.x;
  const int lane = tid & 63;
  const int wave = tid >> 6;
  const int wm = (wave >> 1) * 64;
  const int wn = (wave & 1) * 64;
  const int lm = lane & 15;
  const int quad = lane >> 4;

  float ewp[4], ewm[4], nump[4], numm[4], b1v[4];
#pragma unroll
  for (int j = 0; j < 4; j++) {
    int gh = n0 + wn + j * 16 + lm;
    float w = w3[gh];
    float ep = __expf(2.0f * w);
    float em = __expf(-2.0f * w);
    ewp[j] = ep; ewm[j] = em;
    nump[j] = 128.0f * (1.0f - ep);
    numm[j] = 128.0f * (1.0f - em);
    b1v[j] = b1[gh];
  }
  const size_t coloff = (size_t)((n0 + wn) >> 2) + lm;
#pragma unroll
  for (int i = 0; i < 4; i++) {
#pragma unroll
    for (int r = 0; r < 4; r++) {
      int gb = m0 + wm + i * 16 + quad * 4 + r;
      bool sp = s[gb] > 0.0f;
      float o[4];
#pragma unroll
      for (int j = 0; j < 4; j++) {
        float ews = sp ? ewp[j] : ewm[j];
        float num = sp ? nump[j] : numm[j];
        float z = fminf(acc[i][j][r] + b1v[j], 12.0f);
        float E = __expf(2.0f * z);
        float den = (E * ews + 1.0f) * (E + 1.0f);
        o[j] = (E * num) * __builtin_amdgcn_rcpf(den);  // 64*dh
      }
      int p = __builtin_amdgcn_cvt_pk_fp8_f32(o[0], o[1], 0, false);
      p = __builtin_amdgcn_cvt_pk_fp8_f32(o[2], o[3], p, true);
      Dh4[(size_t)gb * (H_N / 4) + coloff] = (unsigned int)p;
    }
  }
}

// ======= 4-phase pipelined MX-fp8 mainloop for GEMM2 (round-3 verified) ====
// 256x256 tile, 8 waves, double-buffered 2x32KB LDS per operand. Each phase
// loads the NEXT phase's a-fragments (ph3 preloads next tile's b-frags +
// first a-pair from the back buffer) so every MM8 consumes fragments loaded
// one phase earlier. Counted vmcnt (2), never 0 in steady state.
template <int KTOT>
__device__ __forceinline__ void mx8_mainloop(
    const unsigned char* __restrict__ A, const unsigned char* __restrict__ B,
    int m0, int n0, int sa, int sb,
    unsigned char* __restrict__ As, unsigned char* __restrict__ Bs,
    f32x4 (&acc)[8][4]) {
  static_assert(KTOT % 256 == 0, "need an even number of 128-K tiles");
  const int tid = threadIdx.x;
  const int lane = tid & 63;
  const int wave = tid >> 6;
  const int wm = (wave >> 2) * 128;   // 2 waves in M
  const int wn = (wave & 3) * 64;     // 4 waves in N
  const int lm = lane & 15;
  const int quad = lane >> 4;

  const int srow = tid >> 3;
  const int sg = tid & 7;
  const unsigned char* Ag = A + (size_t)(m0 + srow) * KTOT + ((sg ^ (srow & 7)) * 16);
  const unsigned char* Bg = B + (size_t)(n0 + srow) * KTOT + ((sg ^ (srow & 7)) * 16);
  unsigned char* AsW = As + tid * 16;
  unsigned char* BsW = Bs + tid * 16;

  const int e = lm & 7;
  const int lo_off = ((2 * quad) ^ e) * 16;
  const int hi_off = ((2 * quad + 1) ^ e) * 16;
  const unsigned char* Ard_lo = As + (wm + lm) * 128 + lo_off;
  const unsigned char* Ard_hi = As + (wm + lm) * 128 + hi_off;
  const unsigned char* Brd_lo = Bs + (wn + lm) * 128 + lo_off;
  const unsigned char* Brd_hi = Bs + (wn + lm) * 128 + hi_off;

  i32x8 bA0, bA1, bA2, bA3, bB0, bB1, bB2, bB3;
  i32x8 ax0, ax1, ay0, ay1;

#define STGA(c_, kn_, p_) \
    gload16(Ag + (kn_) + (size_t)(c_) * 64 * KTOT, AsW + (p_) * 32768 + (c_) * 8192)
#define STGB(c_, kn_, p_) \
    gload16(Bg + (kn_) + (size_t)(c_) * 64 * KTOT, BsW + (p_) * 32768 + (c_) * 8192)
#define LDA(d_, i_, P_) { \
    i32x4 lo_ = *(const i32x4*)(Ard_lo + (P_) * 32768 + (i_) * 2048); \
    i32x4 hi_ = *(const i32x4*)(Ard_hi + (P_) * 32768 + (i_) * 2048); \
    d_ = __builtin_shufflevector(lo_, hi_, 0, 1, 2, 3, 4, 5, 6, 7); }
#define LDB(d_, j_, P_) { \
    i32x4 lo_ = *(const i32x4*)(Brd_lo + (P_) * 32768 + (j_) * 2048); \
    i32x4 hi_ = *(const i32x4*)(Brd_hi + (P_) * 32768 + (j_) * 2048); \
    d_ = __builtin_shufflevector(lo_, hi_, 0, 1, 2, 3, 4, 5, 6, 7); }
#define MF(a_, b_, c_) \
    __builtin_amdgcn_mfma_scale_f32_16x16x128_f8f6f4((a_), (b_), (c_), 0, 0, 0, sa, 0, sb)
#define BARR() { asm volatile("" ::: "memory"); __builtin_amdgcn_s_barrier(); \
                 asm volatile("" ::: "memory"); }
#define VM(n_) asm volatile("s_waitcnt vmcnt(" #n_ ")" ::: "memory")
#define SCHED0() __builtin_amdgcn_sched_barrier(0)
#define MM8(i0_, i1_, aA_, aB_, B0_, B1_, B2_, B3_) { \
    __builtin_amdgcn_s_setprio(1); \
    acc[i0_][0] = MF(aA_, B0_, acc[i0_][0]); \
    acc[i0_][1] = MF(aA_, B1_, acc[i0_][1]); \
    acc[i0_][2] = MF(aA_, B2_, acc[i0_][2]); \
    acc[i0_][3] = MF(aA_, B3_, acc[i0_][3]); \
    acc[i1_][0] = MF(aB_, B0_, acc[i1_][0]); \
    acc[i1_][1] = MF(aB_, B1_, acc[i1_][1]); \
    acc[i1_][2] = MF(aB_, B2_, acc[i1_][2]); \
    acc[i1_][3] = MF(aB_, B3_, acc[i1_][3]); \
    __builtin_amdgcn_s_setprio(0); }

#define TILE(P_, BC0_, BC1_, BC2_, BC3_, BN0_, BN1_, BN2_, BN3_, kn_, LAST_) { \
    LDA(ay0, 2, P_); LDA(ay1, 3, P_); \
    if (!(LAST_)) { STGB(0, kn_, 1 - (P_)); STGB(1, kn_, 1 - (P_)); } \
    SCHED0(); \
    MM8(0, 1, ax0, ax1, BC0_, BC1_, BC2_, BC3_); \
    if (LAST_) { VM(0); } else { VM(2); } \
    BARR(); \
    LDA(ax0, 4, P_); LDA(ax1, 5, P_); \
    if (!(LAST_)) { STGB(2, kn_, 1 - (P_)); STGB(3, kn_, 1 - (P_)); \
                    STGA(0, kn_, 1 - (P_)); STGA(2, kn_, 1 - (P_)); } \
    SCHED0(); \
    MM8(2, 3, ay0, ay1, BC0_, BC1_, BC2_, BC3_); \
    BARR(); \
    LDA(ay0, 6, P_); LDA(ay1, 7, P_); \
    if (!(LAST_)) { STGA(1, kn_, 1 - (P_)); STGA(3, kn_, 1 - (P_)); } \
    SCHED0(); \
    MM8(4, 5, ax0, ax1, BC0_, BC1_, BC2_, BC3_); \
    if (!(LAST_)) { VM(2); } \
    BARR(); \
    if (!(LAST_)) { \
      LDB(BN0_, 0, 1 - (P_)); LDB(BN1_, 1, 1 - (P_)); \
      LDB(BN2_, 2, 1 - (P_)); LDB(BN3_, 3, 1 - (P_)); \
      LDA(ax0, 0, 1 - (P_)); LDA(ax1, 1, 1 - (P_)); \
    } \
    SCHED0(); \
    MM8(6, 7, ay0, ay1, BC0_, BC1_, BC2_, BC3_); \
    if (!(LAST_)) { BARR(); } \
  }

  STGB(0, 0, 0); STGB(1, 0, 0); STGB(2, 0, 0); STGB(3, 0, 0);
  STGA(0, 0, 0); STGA(2, 0, 0);
  STGA(1, 0, 0); STGA(3, 0, 0);
  VM(2);
  BARR();
  LDB(bA0, 0, 0); LDB(bA1, 1, 0); LDB(bA2, 2, 0); LDB(bA3, 3, 0);
  LDA(ax0, 0, 0); LDA(ax1, 1, 0);

  const int NT = KTOT / 128;
  for (int t = 0; t < NT - 2; t += 2) {
    TILE(0, bA0, bA1, bA2, bA3, bB0, bB1, bB2, bB3, (t + 1) * 128, false);
    TILE(1, bB0, bB1, bB2, bB3, bA0, bA1, bA2, bA3, (t + 2) * 128, false);
  }
  TILE(0, bA0, bA1, bA2, bA3, bB0, bB1, bB2, bB3, (NT - 1) * 128, false);
  TILE(1, bB0, bB1, bB2, bB3, bA0, bA1, bA2, bA3, 0, true);

#undef STGA
#undef STGB
#undef LDA
#undef LDB
#undef MF
#undef BARR
#undef VM
#undef SCHED0
#undef MM8
#undef TILE
}

// ---- GEMM2: Y = Dh @ W2, epilogue mean-scaled sum|Y| -> atomic d_out ----
// Round-3 verified: 256 blocks (64 m x 4 n) of 512 thr = 1 block/CU; same
// m-panel<->XCD map as gemm1 so Dh re-reads hit that XCD's L2.
__global__ __launch_bounds__(512, 2) void gemm2_abs(
    const unsigned char* __restrict__ Dh,    // B_N x H_N fp8 (x64), perm'd K
    const unsigned char* __restrict__ W2T,   // D_N x H_N fp8 (x64), perm'd K
    float* __restrict__ out) {
  __shared__ alignas(16) unsigned char As[65536];
  __shared__ alignas(16) unsigned char Bs[65536];
  __shared__ float wsum[8];
  const int l = blockIdx.x;
  const int x = l & 7;
  const int k = l >> 3;                      // 0..31 per XCD
  const int m0 = (x * 8 + (k & 7)) * 256;
  const int n0 = (k >> 3) * 256;

  f32x4 acc[8][4] = {};
  mx8_mainloop<H_N>(Dh, W2T, m0, n0, 121, 121, As, Bs, acc);  // 2^-6 * 2^-6

  const int tid = threadIdx.x;
  const int lane = tid & 63;
  const int wave = tid >> 6;

  float t = 0.0f;
#pragma unroll
  for (int i = 0; i < 8; i++)
#pragma unroll
    for (int j = 0; j < 4; j++)
#pragma unroll
      for (int r = 0; r < 4; r++)
        t += fabsf(acc[i][j][r]);

#pragma unroll
  for (int off2 = 32; off2 > 0; off2 >>= 1)
    t += __shfl_down(t, off2, 64);
  if (lane == 0) wsum[wave] = t;
  __syncthreads();
  if (tid == 0) {
    float tt = 0.0f;
#pragma unroll
    for (int w = 0; w < 8; w++) tt += wsum[w];
    atomicAdd(out, tt * (1.0f / (float)B_N));
  }
}

extern "C" void kernel_launch(void* const* d_in, const int* in_sizes, int n_in,
                              void* d_out, int out_size, void* d_ws, size_t ws_size,
                              hipStream_t stream) {
  const float* X  = (const float*)d_in[0];
  const float* W1 = (const float*)d_in[1];
  const float* b1 = (const float*)d_in[2];
  const float* W2 = (const float*)d_in[3];
  // d_in[4] = b2 : cancels in the difference
  const int* pci  = (const int*)d_in[5];

  char* ws = (char*)d_ws;
  size_t off = 0;
  unsigned char* Xb  = (unsigned char*)(ws + off); off += (size_t)B_N * D_N;
  unsigned char* W1T = (unsigned char*)(ws + off); off += (size_t)H_N * D_N;
  unsigned char* W2T = (unsigned char*)(ws + off); off += (size_t)D_N * H_N;
  float* w3  = (float*)(ws + off); off += (size_t)H_N * 4;
  float* s   = (float*)(ws + off); off += (size_t)B_N * 4;
  unsigned char* Dh  = (unsigned char*)(ws + off); off += (size_t)B_N * H_N;
  if (ws_size < off) return;

  prep_kernel<<<16384, 256, 0, stream>>>((const float4*)X, (int*)Xb, s,
                                         W1, W1T, w3, W2, W2T, pci,
                                         (float*)d_out);
  gemm1_dh<<<dim3(32, 128), 256, 0, stream>>>(Xb, W1T, b1, w3, s,
                                              (unsigned int*)Dh);
  gemm2_abs<<<256, 512, 0, stream>>>(Dh, W2T, (float*)d_out);
}

// Round 10
// 273.153 us; speedup vs baseline: 3.4540x; 1.0106x over previous
//
#include <hip/hip_runtime.h>
#include <stdint.h>

#define B_N 16384
#define D_N 1024
#define H_N 4096

typedef int i32x4 __attribute__((ext_vector_type(4)));
typedef int i32x8 __attribute__((ext_vector_type(8)));
typedef float f32x4 __attribute__((ext_vector_type(4)));

__device__ __forceinline__ void gload16(const void* g, void* l) {
  __builtin_amdgcn_global_load_lds((const __attribute__((address_space(1))) void*)g,
                                   (__attribute__((address_space(3))) void*)l,
                                   16, 0, 0);
}

__device__ __forceinline__ unsigned char f2fp8(float v) {
  return (unsigned char)(__builtin_amdgcn_cvt_pk_fp8_f32(v, v, 0, false) & 0xFF);
}

// within-64-block H permutation used for Dh stores / W2T K-index:
// u = j*16+lm  ->  lm*4+j
__device__ __forceinline__ int perm_h(int h) {
  return (h & ~63) | ((h & 15) << 2) | ((h >> 4) & 3);
}

// ================= prep (single dispatch): pack X, transpose W1/W2 =========
__device__ __forceinline__ void transpose_tile(
    const float* __restrict__ in, unsigned char* __restrict__ out,
    int R, int C, float scale, float* __restrict__ w3, int pci,
    int i0, int j0, int tx, int ty, bool permute) {
  __shared__ float tile[32][33];
#pragma unroll
  for (int r = 0; r < 32; r += 8) {
    int i = i0 + ty + r;
    int j = j0 + tx;
    float v = in[(size_t)i * C + j];
    tile[ty + r][tx] = v;
    if (w3 != nullptr && i == pci) w3[j] = v;
  }
  __syncthreads();
#pragma unroll
  for (int r = 0; r < 32; r += 8) {
    int jo = j0 + ty + r;
    int io = i0 + tx;
    int ioo = permute ? perm_h(io) : io;
    out[(size_t)jo * R + ioo] = f2fp8(tile[tx][ty + r] * scale);
  }
}

__global__ __launch_bounds__(256) void prep_kernel(
    const float4* __restrict__ X4, int* __restrict__ Xb,
    float* __restrict__ s,
    const float* __restrict__ W1, unsigned char* __restrict__ W1T, float* __restrict__ w3,
    const float* __restrict__ W2, unsigned char* __restrict__ W2T,
    const int* __restrict__ pci_p, float* __restrict__ out0) {
  int b = blockIdx.x;
  int tid = threadIdx.x;
  int pci = *pci_p;
  if (b == 0 && tid == 0) out0[0] = 0.0f;   // zero the output accumulator
  if (b < 8192) {
    int i = (b * 256 + tid) * 2;
#pragma unroll
    for (int u = 0; u < 2; u++) {
      float4 v = X4[i + u];
      int p = __builtin_amdgcn_cvt_pk_fp8_f32(v.x, v.y, 0, false);
      p = __builtin_amdgcn_cvt_pk_fp8_f32(v.z, v.w, p, true);
      Xb[i + u] = p;
      if (((i + u) & (D_N / 4 - 1)) == (pci >> 2)) {
        int row = (i + u) >> 8;
        float c;
        switch (pci & 3) {
          case 0:  c = v.x; break;
          case 1:  c = v.y; break;
          case 2:  c = v.z; break;
          default: c = v.w; break;
        }
        s[row] = 1.0f - 2.0f * c;
      }
    }
  } else if (b < 12288) {
    // W1 (D_N x H_N) -> W1T[h][d] = W1[d][h]*16 ; rows h NOT permuted
    int id = b - 8192;
    transpose_tile(W1, W1T, D_N, H_N, 16.0f, w3, pci,
                   (id >> 7) * 32, (id & 127) * 32, tid & 31, tid >> 5, false);
  } else {
    // W2 (H_N x D_N) -> W2T[d][perm(h)] = W2[h][d]*64 ; K(=H) permuted
    int id = b - 12288;
    transpose_tile(W2, W2T, H_N, D_N, 64.0f, nullptr, -1,
                   (id >> 5) * 32, (id & 31) * 32, tid & 31, tid >> 5, true);
  }
}

// == GEMM1 mainloop: 128x128 tile, TWO waves of 64x128, 4 blocks/CU ========
// Same staging/sync/swizzle as the verified baseline; only the wave->output
// decomposition changes: each wave owns 64 rows x ALL 128 cols, so per
// K-tile a wave reads 4 A-frags + 8 B-frags (12) and issues 32 MFMAs
// (2.67 MFMA/frag-read vs 2.0 for 64x64), and both waves share B rows ->
// block LDS reads drop 256->192 b128 per CU-window. acc[4][8] = 128 AGPR;
// with a-frags(32)+b(8..16)+addr(~20) total ~210 < 256 regs at
// __launch_bounds__(128,2) -> 4 blocks/CU, 8 waves/CU from 4 independent
// blocks (inter-block overlap covers the staging drain).
// Thread-constant XOR (e=lm&7) makes every LDS read base+immediate.
template <int KTOT>
__device__ __forceinline__ void mx_w2_mainloop(
    const unsigned char* __restrict__ A, const unsigned char* __restrict__ B,
    int m0, int n0, int sa, int sb,
    unsigned char* As, unsigned char* Bs, f32x4 (&acc)[4][8]) {
  const int tid = threadIdx.x;
  const int lane = tid & 63;
  const int wave = tid >> 6;      // 0..1
  const int wm = wave * 64;
  const int lm = lane & 15;
  const int quad = lane >> 4;

  // staging: 128 threads cover 16 rows/iter, 8 iters per 128-row operand
  const int srow = tid >> 3;      // 0..15
  const int clog = (tid & 7) ^ (srow & 7);   // row&7 == srow&7 for all iters
  const unsigned char* Ag = A + (size_t)(m0 + srow) * KTOT + clog * 16;
  const unsigned char* Bg = B + (size_t)(n0 + srow) * KTOT + clog * 16;
  unsigned char* As_l = As + tid * 16;
  unsigned char* Bs_l = Bs + tid * 16;

  // fragment-read bases: e = lm&7 thread-constant for ALL fragments
  const int e = lm & 7;
  const unsigned char* Ard_lo = As + (wm + lm) * 128 + (((2 * quad) ^ e) * 16);
  const unsigned char* Ard_hi = As + (wm + lm) * 128 + (((2 * quad + 1) ^ e) * 16);
  const unsigned char* Brd_lo = Bs + lm * 128 + (((2 * quad) ^ e) * 16);
  const unsigned char* Brd_hi = Bs + lm * 128 + (((2 * quad + 1) ^ e) * 16);

  for (int k0 = 0; k0 < KTOT; k0 += 128) {
#pragma unroll
    for (int it = 0; it < 8; it++) {
      gload16(Ag + k0 + (size_t)(16 * it) * KTOT, As_l + it * 2048);
      gload16(Bg + k0 + (size_t)(16 * it) * KTOT, Bs_l + it * 2048);
    }
    __syncthreads();
    i32x8 a[4];
#pragma unroll
    for (int i = 0; i < 4; i++) {
      i32x4 lo = *(const i32x4*)(Ard_lo + i * 2048);
      i32x4 hi = *(const i32x4*)(Ard_hi + i * 2048);
      a[i] = __builtin_shufflevector(lo, hi, 0, 1, 2, 3, 4, 5, 6, 7);
    }
#pragma unroll
    for (int j = 0; j < 8; j++) {
      i32x4 lo = *(const i32x4*)(Brd_lo + j * 2048);
      i32x4 hi = *(const i32x4*)(Brd_hi + j * 2048);
      i32x8 b = __builtin_shufflevector(lo, hi, 0, 1, 2, 3, 4, 5, 6, 7);
#pragma unroll
      for (int i = 0; i < 4; i++)
        acc[i][j] = __builtin_amdgcn_mfma_scale_f32_16x16x128_f8f6f4(
            a[i], b, acc[i][j], 0, 0, 0, sa, 0, sb);
    }
    __syncthreads();
  }
}

// ---- GEMM1: Z = X @ W1, epilogue Dh = 64*(tanh(z)-tanh(z+s*w3)) -> fp8 ----
// Grid 4096 blocks of 128 thr = 4 generations at 4 blocks/CU. Same tile->XCD
// map as before (x = l&7 owns m-panels; W1T n-slice L2-hot per generation).
__global__ __launch_bounds__(128, 2) void gemm1_dh(
    const unsigned char* __restrict__ Xb,    // B_N x D_N fp8 (x1)
    const unsigned char* __restrict__ W1T,   // H_N x D_N fp8 (x16)
    const float* __restrict__ b1,
    const float* __restrict__ w3,            // H_N : W1[pci][h] f32
    const float* __restrict__ s,             // B_N : 1-2*col
    unsigned int* __restrict__ Dh4) {        // B_N x H_N fp8 (x64), perm'd cols
  __shared__ alignas(16) unsigned char As[128 * 128];
  __shared__ alignas(16) unsigned char Bs[128 * 128];
  int l = blockIdx.y * gridDim.x + blockIdx.x;  // HW dispatch-linear
  int x = l & 7;                                // XCD round-robin
  int k = l >> 3;                               // 0..511 per XCD
  int ni = k & 7;
  int m  = (k >> 3) & 15;
  int nc = k >> 7;                              // 0..3
  const int m0 = (x * 16 + m) * 128;
  const int n0 = (nc * 8 + ni) * 128;

  f32x4 acc[4][8] = {};
  mx_w2_mainloop<D_N>(Xb, W1T, m0, n0, 127, 123, As, Bs, acc);  // 2^0 * 2^-4

  const int tid = threadIdx.x;
  const int lane = tid & 63;
  const int wave = tid >> 6;
  const int wm = wave * 64;
  const int lm = lane & 15;
  const int quad = lane >> 4;

  float ewp[8], ewm[8], nump[8], numm[8], b1v[8];
#pragma unroll
  for (int j = 0; j < 8; j++) {
    int gh = n0 + j * 16 + lm;
    float w = w3[gh];
    float ep = __expf(2.0f * w);
    float em = __expf(-2.0f * w);
    ewp[j] = ep; ewm[j] = em;
    nump[j] = 128.0f * (1.0f - ep);
    numm[j] = 128.0f * (1.0f - em);
    b1v[j] = b1[gh];
  }
  const size_t col0 = (size_t)(n0 >> 2) + lm;   // 64-col block 0; block 1 = +16
#pragma unroll
  for (int i = 0; i < 4; i++) {
#pragma unroll
    for (int r = 0; r < 4; r++) {
      int gb = m0 + wm + i * 16 + quad * 4 + r;
      bool sp = s[gb] > 0.0f;
      float o[8];
#pragma unroll
      for (int j = 0; j < 8; j++) {
        float ews = sp ? ewp[j] : ewm[j];
        float num = sp ? nump[j] : numm[j];
        float z = fminf(acc[i][j][r] + b1v[j], 12.0f);
        float E = __expf(2.0f * z);
        float den = (E * ews + 1.0f) * (E + 1.0f);
        o[j] = (E * num) * __builtin_amdgcn_rcpf(den);  // 64*dh
      }
      int p0 = __builtin_amdgcn_cvt_pk_fp8_f32(o[0], o[1], 0, false);
      p0 = __builtin_amdgcn_cvt_pk_fp8_f32(o[2], o[3], p0, true);
      int p1 = __builtin_amdgcn_cvt_pk_fp8_f32(o[4], o[5], 0, false);
      p1 = __builtin_amdgcn_cvt_pk_fp8_f32(o[6], o[7], p1, true);
      Dh4[(size_t)gb * (H_N / 4) + col0] = (unsigned int)p0;
      Dh4[(size_t)gb * (H_N / 4) + col0 + 16] = (unsigned int)p1;
    }
  }
}

// ======= 4-phase pipelined MX-fp8 mainloop for GEMM2 (round-3 verified) ====
// 256x256 tile, 8 waves, double-buffered 2x32KB LDS per operand. Each phase
// loads the NEXT phase's a-fragments (ph3 preloads next tile's b-frags +
// first a-pair from the back buffer) so every MM8 consumes fragments loaded
// one phase earlier. Counted vmcnt (2), never 0 in steady state.
template <int KTOT>
__device__ __forceinline__ void mx8_mainloop(
    const unsigned char* __restrict__ A, const unsigned char* __restrict__ B,
    int m0, int n0, int sa, int sb,
    unsigned char* __restrict__ As, unsigned char* __restrict__ Bs,
    f32x4 (&acc)[8][4]) {
  static_assert(KTOT % 256 == 0, "need an even number of 128-K tiles");
  const int tid = threadIdx.x;
  const int lane = tid & 63;
  const int wave = tid >> 6;
  const int wm = (wave >> 2) * 128;   // 2 waves in M
  const int wn = (wave & 3) * 64;     // 4 waves in N
  const int lm = lane & 15;
  const int quad = lane >> 4;

  const int srow = tid >> 3;
  const int sg = tid & 7;
  const unsigned char* Ag = A + (size_t)(m0 + srow) * KTOT + ((sg ^ (srow & 7)) * 16);
  const unsigned char* Bg = B + (size_t)(n0 + srow) * KTOT + ((sg ^ (srow & 7)) * 16);
  unsigned char* AsW = As + tid * 16;
  unsigned char* BsW = Bs + tid * 16;

  const int e = lm & 7;
  const int lo_off = ((2 * quad) ^ e) * 16;
  const int hi_off = ((2 * quad + 1) ^ e) * 16;
  const unsigned char* Ard_lo = As + (wm + lm) * 128 + lo_off;
  const unsigned char* Ard_hi = As + (wm + lm) * 128 + hi_off;
  const unsigned char* Brd_lo = Bs + (wn + lm) * 128 + lo_off;
  const unsigned char* Brd_hi = Bs + (wn + lm) * 128 + hi_off;

  i32x8 bA0, bA1, bA2, bA3, bB0, bB1, bB2, bB3;
  i32x8 ax0, ax1, ay0, ay1;

#define STGA(c_, kn_, p_) \
    gload16(Ag + (kn_) + (size_t)(c_) * 64 * KTOT, AsW + (p_) * 32768 + (c_) * 8192)
#define STGB(c_, kn_, p_) \
    gload16(Bg + (kn_) + (size_t)(c_) * 64 * KTOT, BsW + (p_) * 32768 + (c_) * 8192)
#define LDA(d_, i_, P_) { \
    i32x4 lo_ = *(const i32x4*)(Ard_lo + (P_) * 32768 + (i_) * 2048); \
    i32x4 hi_ = *(const i32x4*)(Ard_hi + (P_) * 32768 + (i_) * 2048); \
    d_ = __builtin_shufflevector(lo_, hi_, 0, 1, 2, 3, 4, 5, 6, 7); }
#define LDB(d_, j_, P_) { \
    i32x4 lo_ = *(const i32x4*)(Brd_lo + (P_) * 32768 + (j_) * 2048); \
    i32x4 hi_ = *(const i32x4*)(Brd_hi + (P_) * 32768 + (j_) * 2048); \
    d_ = __builtin_shufflevector(lo_, hi_, 0, 1, 2, 3, 4, 5, 6, 7); }
#define MF(a_, b_, c_) \
    __builtin_amdgcn_mfma_scale_f32_16x16x128_f8f6f4((a_), (b_), (c_), 0, 0, 0, sa, 0, sb)
#define BARR() { asm volatile("" ::: "memory"); __builtin_amdgcn_s_barrier(); \
                 asm volatile("" ::: "memory"); }
#define VM(n_) asm volatile("s_waitcnt vmcnt(" #n_ ")" ::: "memory")
#define SCHED0() __builtin_amdgcn_sched_barrier(0)
#define MM8(i0_, i1_, aA_, aB_, B0_, B1_, B2_, B3_) { \
    __builtin_amdgcn_s_setprio(1); \
    acc[i0_][0] = MF(aA_, B0_, acc[i0_][0]); \
    acc[i0_][1] = MF(aA_, B1_, acc[i0_][1]); \
    acc[i0_][2] = MF(aA_, B2_, acc[i0_][2]); \
    acc[i0_][3] = MF(aA_, B3_, acc[i0_][3]); \
    acc[i1_][0] = MF(aB_, B0_, acc[i1_][0]); \
    acc[i1_][1] = MF(aB_, B1_, acc[i1_][1]); \
    acc[i1_][2] = MF(aB_, B2_, acc[i1_][2]); \
    acc[i1_][3] = MF(aB_, B3_, acc[i1_][3]); \
    __builtin_amdgcn_s_setprio(0); }

#define TILE(P_, BC0_, BC1_, BC2_, BC3_, BN0_, BN1_, BN2_, BN3_, kn_, LAST_) { \
    LDA(ay0, 2, P_); LDA(ay1, 3, P_); \
    if (!(LAST_)) { STGB(0, kn_, 1 - (P_)); STGB(1, kn_, 1 - (P_)); } \
    SCHED0(); \
    MM8(0, 1, ax0, ax1, BC0_, BC1_, BC2_, BC3_); \
    if (LAST_) { VM(0); } else { VM(2); } \
    BARR(); \
    LDA(ax0, 4, P_); LDA(ax1, 5, P_); \
    if (!(LAST_)) { STGB(2, kn_, 1 - (P_)); STGB(3, kn_, 1 - (P_)); \
                    STGA(0, kn_, 1 - (P_)); STGA(2, kn_, 1 - (P_)); } \
    SCHED0(); \
    MM8(2, 3, ay0, ay1, BC0_, BC1_, BC2_, BC3_); \
    BARR(); \
    LDA(ay0, 6, P_); LDA(ay1, 7, P_); \
    if (!(LAST_)) { STGA(1, kn_, 1 - (P_)); STGA(3, kn_, 1 - (P_)); } \
    SCHED0(); \
    MM8(4, 5, ax0, ax1, BC0_, BC1_, BC2_, BC3_); \
    if (!(LAST_)) { VM(2); } \
    BARR(); \
    if (!(LAST_)) { \
      LDB(BN0_, 0, 1 - (P_)); LDB(BN1_, 1, 1 - (P_)); \
      LDB(BN2_, 2, 1 - (P_)); LDB(BN3_, 3, 1 - (P_)); \
      LDA(ax0, 0, 1 - (P_)); LDA(ax1, 1, 1 - (P_)); \
    } \
    SCHED0(); \
    MM8(6, 7, ay0, ay1, BC0_, BC1_, BC2_, BC3_); \
    if (!(LAST_)) { BARR(); } \
  }

  STGB(0, 0, 0); STGB(1, 0, 0); STGB(2, 0, 0); STGB(3, 0, 0);
  STGA(0, 0, 0); STGA(2, 0, 0);
  STGA(1, 0, 0); STGA(3, 0, 0);
  VM(2);
  BARR();
  LDB(bA0, 0, 0); LDB(bA1, 1, 0); LDB(bA2, 2, 0); LDB(bA3, 3, 0);
  LDA(ax0, 0, 0); LDA(ax1, 1, 0);

  const int NT = KTOT / 128;
  for (int t = 0; t < NT - 2; t += 2) {
    TILE(0, bA0, bA1, bA2, bA3, bB0, bB1, bB2, bB3, (t + 1) * 128, false);
    TILE(1, bB0, bB1, bB2, bB3, bA0, bA1, bA2, bA3, (t + 2) * 128, false);
  }
  TILE(0, bA0, bA1, bA2, bA3, bB0, bB1, bB2, bB3, (NT - 1) * 128, false);
  TILE(1, bB0, bB1, bB2, bB3, bA0, bA1, bA2, bA3, 0, true);

#undef STGA
#undef STGB
#undef LDA
#undef LDB
#undef MF
#undef BARR
#undef VM
#undef SCHED0
#undef MM8
#undef TILE
}

// ---- GEMM2: Y = Dh @ W2, epilogue mean-scaled sum|Y| -> atomic d_out ----
// Round-3 verified: 256 blocks (64 m x 4 n) of 512 thr = 1 block/CU; same
// m-panel<->XCD map as gemm1 so Dh re-reads hit that XCD's L2.
__global__ __launch_bounds__(512, 2) void gemm2_abs(
    const unsigned char* __restrict__ Dh,    // B_N x H_N fp8 (x64), perm'd K
    const unsigned char* __restrict__ W2T,   // D_N x H_N fp8 (x64), perm'd K
    float* __restrict__ out) {
  __shared__ alignas(16) unsigned char As[65536];
  __shared__ alignas(16) unsigned char Bs[65536];
  __shared__ float wsum[8];
  const int l = blockIdx.x;
  const int x = l & 7;
  const int k = l >> 3;                      // 0..31 per XCD
  const int m0 = (x * 8 + (k & 7)) * 256;
  const int n0 = (k >> 3) * 256;

  f32x4 acc[8][4] = {};
  mx8_mainloop<H_N>(Dh, W2T, m0, n0, 121, 121, As, Bs, acc);  // 2^-6 * 2^-6

  const int tid = threadIdx.x;
  const int lane = tid & 63;
  const int wave = tid >> 6;

  float t = 0.0f;
#pragma unroll
  for (int i = 0; i < 8; i++)
#pragma unroll
    for (int j = 0; j < 4; j++)
#pragma unroll
      for (int r = 0; r < 4; r++)
        t += fabsf(acc[i][j][r]);

#pragma unroll
  for (int off2 = 32; off2 > 0; off2 >>= 1)
    t += __shfl_down(t, off2, 64);
  if (lane == 0) wsum[wave] = t;
  __syncthreads();
  if (tid == 0) {
    float tt = 0.0f;
#pragma unroll
    for (int w = 0; w < 8; w++) tt += wsum[w];
    atomicAdd(out, tt * (1.0f / (float)B_N));
  }
}

extern "C" void kernel_launch(void* const* d_in, const int* in_sizes, int n_in,
                              void* d_out, int out_size, void* d_ws, size_t ws_size,
                              hipStream_t stream) {
  const float* X  = (const float*)d_in[0];
  const float* W1 = (const float*)d_in[1];
  const float* b1 = (const float*)d_in[2];
  const float* W2 = (const float*)d_in[3];
  // d_in[4] = b2 : cancels in the difference
  const int* pci  = (const int*)d_in[5];

  char* ws = (char*)d_ws;
  size_t off = 0;
  unsigned char* Xb  = (unsigned char*)(ws + off); off += (size_t)B_N * D_N;
  unsigned char* W1T = (unsigned char*)(ws + off); off += (size_t)H_N * D_N;
  unsigned char* W2T = (unsigned char*)(ws + off); off += (size_t)D_N * H_N;
  float* w3  = (float*)(ws + off); off += (size_t)H_N * 4;
  float* s   = (float*)(ws + off); off += (size_t)B_N * 4;
  unsigned char* Dh  = (unsigned char*)(ws + off); off += (size_t)B_N * H_N;
  if (ws_size < off) return;

  prep_kernel<<<16384, 256, 0, stream>>>((const float4*)X, (int*)Xb, s,
                                         W1, W1T, w3, W2, W2T, pci,
                                         (float*)d_out);
  gemm1_dh<<<dim3(32, 128), 128, 0, stream>>>(Xb, W1T, b1, w3, s,
                                              (unsigned int*)Dh);
  gemm2_abs<<<256, 512, 0, stream>>>(Dh, W2T, (float*)d_out);
}